// Round 6
// baseline (619.220 us; speedup 1.0000x reference)
//
#include <hip/hip_runtime.h>
#include <hip/hip_bf16.h>

// PermutationGenerator: B=8192, N=64, D=128, LATENT=256, TEMP=0.1, 20 Sinkhorn iters.
// d_in (ALL f32): [0] padded [B][64][128], [1] set_size int32 [B], [2] maskB (UNUSED),
//       [3] gumbel [B][64][64], [4] W1 [128][256], [5] b1 [256],
//       [6] W2 [256][64], [7] b2 [64]
// d_out f32: [0:8192] set_size, then permuted [B][64][128].
//
// R5 structure: ONE WAVE PER BATCH, zero barriers.
//  - GEMM1 computes h^T in 32-latent slabs (A=W1^T, B=x^T both direct-from-global).
//  - GEMM2 computes net^T (A=W2^T); h^T D-frag -> B-frag via 16x ds_bpermute.
//  - Sinkhorn fully in-register on net^T layout (shfl_xor row-dim, DPP col-dim).
//  - GEMM3 P^T via per-wave private 8KB subtiled LDS ([i>>3][j][i&7], b128 reads
//    conflict-free); B = x scatter loads; direct dword stores.

typedef _Float16 h16;
typedef h16 h8 __attribute__((ext_vector_type(8)));
typedef __fp16 fp16x2 __attribute__((ext_vector_type(2)));
typedef float v4f __attribute__((ext_vector_type(4)));

template<int CTRL>
__device__ __forceinline__ float dppf(float x) {
  return __int_as_float(__builtin_amdgcn_update_dpp(
      0, __float_as_int(x), CTRL, 0xF, 0xF, true));
}
// sum over each 16-lane group: quad xor1, quad xor2, row_ror:4, row_ror:8
__device__ __forceinline__ float red16_sum(float x) {
  x += dppf<0xB1>(x);
  x += dppf<0x4E>(x);
  x += dppf<0x124>(x);
  x += dppf<0x128>(x);
  return x;
}
__device__ __forceinline__ float frcp(float x) { return __builtin_amdgcn_rcpf(x); }
__device__ __forceinline__ float bperm(int addr, float v) {
  return __int_as_float(__builtin_amdgcn_ds_bpermute(addr, __float_as_int(v)));
}
__device__ __forceinline__ h8 cvt8(v4f a, v4f b) {
  union { h8 v; fp16x2 p[4]; } u;
  u.p[0] = __builtin_amdgcn_cvt_pkrtz(a[0], a[1]);
  u.p[1] = __builtin_amdgcn_cvt_pkrtz(a[2], a[3]);
  u.p[2] = __builtin_amdgcn_cvt_pkrtz(b[0], b[1]);
  u.p[3] = __builtin_amdgcn_cvt_pkrtz(b[2], b[3]);
  return u.v;
}

__global__ __launch_bounds__(256) void prep_w(const float* __restrict__ W1,
                                              const float* __restrict__ W2,
                                              h16* __restrict__ w1t,
                                              h16* __restrict__ w2t) {
  int t = blockIdx.x * 256 + threadIdx.x;
  if (t < 128 * 256) {               // W1 [128][256] -> w1t [256 lat][128 f]
    int kq = t >> 8, n = t & 255;
    w1t[n * 128 + kq] = (h16)W1[t];
  } else if (t < 128 * 256 + 256 * 64) {  // W2 [256][64] -> w2t [64 j][256 lat]
    int t2 = t - 128 * 256;
    int kq = t2 >> 6, n = t2 & 63;
    w2t[n * 256 + kq] = (h16)W2[t2];
  }
}

// Runs LAST on the stream.
__global__ __launch_bounds__(256) void write_ss(const int* __restrict__ ssz,
                                                float* __restrict__ outp) {
  int b = blockIdx.x * 256 + threadIdx.x;
  if (b < 8192) outp[b] = (float)ssz[b];
}

template<bool WSF>
__global__ __launch_bounds__(256, 3) void permgen_wave(
    const float* __restrict__ xf,   // f32 [B][64][128]
    const int* __restrict__ ssz,
    const float* __restrict__ gn,
    const float* __restrict__ b1,
    const float* __restrict__ b2,
    const h16* __restrict__ w1t,   // [256][128] (only if WSF)
    const h16* __restrict__ w2t,   // [64][256]  (only if WSF)
    const float* __restrict__ W1f,
    const float* __restrict__ W2f,
    float* __restrict__ outp) {
  // per-wave private 8KB: P^T subtiled [i>>3][j][i&7] f16
  __shared__ h16 pth_all[4][4096];

  const int tid = threadIdx.x;
  const int w = tid >> 6;
  const int lane = tid & 63;
  const int g = lane >> 4;
  const int lc = lane & 15;
  h16* pth = pth_all[w];

  const int b = blockIdx.x * 4 + w;
  const int k = ssz[b];
  const int mcnt = (k + 15) >> 4;      // valid 16-tiles
  const int kk3max = (k + 31) >> 5;    // valid 32-slices
  const float* xb = xf + (size_t)b * 8192;

  // bpermute source lanes for h^T D-frag -> B-frag redistribution
  const int srcA = ((2 * (g & 1)) * 16 + lc) * 4;  // elems 0..3
  const int srcB = srcA + 64;                      // elems 4..7

  // p[mj][nr] = net^T then P: element q -> P[row r=16nr+lc][col j=16mj+4g+q]
  v4f p[4][4];
#pragma unroll
  for (int mj = 0; mj < 4; ++mj)
#pragma unroll
    for (int nr = 0; nr < 4; ++nr) p[mj][nr] = (v4f){0.f, 0.f, 0.f, 0.f};

  // ================= MLP: net^T accumulation over 8 slabs of 32 latents ======
#pragma unroll 1
  for (int lb = 0; lb < 8; ++lb) {
    v4f accT[2][4];
#pragma unroll
    for (int mt = 0; mt < 2; ++mt)
#pragma unroll
      for (int nr = 0; nr < 4; ++nr) accT[mt][nr] = (v4f){0.f, 0.f, 0.f, 0.f};

#pragma unroll
    for (int kk = 0; kk < 4; ++kk) {
      h8 aw[2];
#pragma unroll
      for (int mt = 0; mt < 2; ++mt) {
        if (WSF) {
          aw[mt] = *(const h8*)&w1t[(lb * 32 + 16 * mt + lc) * 128 + kk * 32 + 8 * g];
        } else {
          h8 t;
#pragma unroll
          for (int e = 0; e < 8; ++e)
            t[e] = (h16)W1f[(kk * 32 + 8 * g + e) * 256 + lb * 32 + 16 * mt + lc];
          aw[mt] = t;
        }
      }
#pragma unroll
      for (int nr = 0; nr < 4; ++nr)
        if (nr < mcnt) {
          const float* px = xb + (16 * nr + lc) * 128 + kk * 32 + 8 * g;
          h8 bx = cvt8(*(const v4f*)px, *(const v4f*)(px + 4));
          accT[0][nr] = __builtin_amdgcn_mfma_f32_16x16x32_f16(aw[0], bx, accT[0][nr], 0, 0, 0);
          accT[1][nr] = __builtin_amdgcn_mfma_f32_16x16x32_f16(aw[1], bx, accT[1][nr], 0, 0, 0);
        }
    }

    // bias + relu -> ht (h^T D-frag: ht[mt][nr][q] = h^T[lb*32+16mt+4g+q][16nr+lc])
    v4f b1a = *(const v4f*)&b1[lb * 32 + 4 * g];
    v4f b1b = *(const v4f*)&b1[lb * 32 + 16 + 4 * g];
    float ht0[4][4], ht1[4][4];
#pragma unroll
    for (int nr = 0; nr < 4; ++nr)
      if (nr < mcnt)
#pragma unroll
        for (int q = 0; q < 4; ++q) {
          ht0[nr][q] = fmaxf(accT[0][nr][q] + b1a[q], 0.0f);
          ht1[nr][q] = fmaxf(accT[1][nr][q] + b1b[q], 0.0f);
        }

    // GEMM2 partial: A = W2^T rows j, B = h^T (k=32 slab)
    h8 aj[4];
#pragma unroll
    for (int mj = 0; mj < 4; ++mj)
      if (mj < mcnt) {
        if (WSF) {
          aj[mj] = *(const h8*)&w2t[(16 * mj + lc) * 256 + lb * 32 + 8 * g];
        } else {
          h8 t;
#pragma unroll
          for (int e = 0; e < 8; ++e)
            t[e] = (h16)W2f[(lb * 32 + 8 * g + e) * 64 + 16 * mj + lc];
          aj[mj] = t;
        }
      }
#pragma unroll
    for (int nr = 0; nr < 4; ++nr)
      if (nr < mcnt) {
        float hv[8];
#pragma unroll
        for (int e = 0; e < 8; ++e) {
          const int a_ = (e < 4) ? srcA : srcB;
          float v0 = bperm(a_, ht0[nr][e & 3]);
          float v1 = bperm(a_, ht1[nr][e & 3]);
          hv[e] = (g >= 2) ? v1 : v0;
        }
        h8 bh = cvt8((v4f){hv[0], hv[1], hv[2], hv[3]},
                     (v4f){hv[4], hv[5], hv[6], hv[7]});
#pragma unroll
        for (int mj = 0; mj < 4; ++mj)
          if (mj < mcnt)
            p[mj][nr] = __builtin_amdgcn_mfma_f32_16x16x32_f16(aj[mj], bh, p[mj][nr], 0, 0, 0);
      }
  }

  // ================= Sinkhorn init: la -> exp(la - rowmax), masked -> 0 ======
  v4f b2j[4];
#pragma unroll
  for (int mj = 0; mj < 4; ++mj) b2j[mj] = *(const v4f*)&b2[16 * mj + 4 * g];

#pragma unroll
  for (int nr = 0; nr < 4; ++nr)
    if (nr < mcnt) {
      const int r = 16 * nr + lc;
#pragma unroll
      for (int mj = 0; mj < 4; ++mj)
        if (mj < mcnt) {
          v4f gv = *(const v4f*)(gn + (size_t)b * 4096 + r * 64 + 16 * mj + 4 * g);
#pragma unroll
          for (int q = 0; q < 4; ++q) {
            const int j = 16 * mj + 4 * g + q;
            const float la = p[mj][nr][q] + b2j[mj][q] + gv[q];
            p[mj][nr][q] = (r < k && j < k) ? la : -1e30f;
          }
        }
      // rowmax over j (in-lane mj,q + cross-group)
      float m_ = -1e30f;
#pragma unroll
      for (int mj = 0; mj < 4; ++mj)
        if (mj < mcnt)
#pragma unroll
          for (int q = 0; q < 4; ++q) m_ = fmaxf(m_, p[mj][nr][q]);
      m_ = fmaxf(m_, __shfl_xor(m_, 16));
      m_ = fmaxf(m_, __shfl_xor(m_, 32));
#pragma unroll
      for (int mj = 0; mj < 4; ++mj)
        if (mj < mcnt)
#pragma unroll
          for (int q = 0; q < 4; ++q) {
            const float la = p[mj][nr][q];
            // la*10/TEMP folded into exp2: *10*log2(e)
            p[mj][nr][q] = (la > -1e29f) ? exp2f((la - m_) * 14.4269504089f) : 0.0f;
          }
    }

  // ================= 20 Sinkhorn iterations, fully in-wave ===================
#pragma unroll 1
  for (int it = 0; it < 20; ++it) {
    // row-normalize (over j): in-lane (mj,q) + shfl_xor across groups
#pragma unroll
    for (int nr = 0; nr < 4; ++nr)
      if (nr < mcnt) {
        float s = 0.0f;
#pragma unroll
        for (int mj = 0; mj < 4; ++mj)
          if (mj < mcnt)
            s += (p[mj][nr][0] + p[mj][nr][1]) + (p[mj][nr][2] + p[mj][nr][3]);
        s += __shfl_xor(s, 16);
        s += __shfl_xor(s, 32);
        const float sc = frcp(s + 1e-30f);
#pragma unroll
        for (int mj = 0; mj < 4; ++mj)
          if (mj < mcnt) {
            p[mj][nr][0] *= sc; p[mj][nr][1] *= sc;
            p[mj][nr][2] *= sc; p[mj][nr][3] *= sc;
          }
      }
    // col-normalize (over r): in-lane (nr) + DPP across 16 lanes
#pragma unroll
    for (int mj = 0; mj < 4; ++mj)
      if (mj < mcnt) {
#pragma unroll
        for (int q = 0; q < 4; ++q) {
          float c = 0.0f;
#pragma unroll
          for (int nr = 0; nr < 4; ++nr)
            if (nr < mcnt) c += p[mj][nr][q];
          c = red16_sum(c);
          const float sc = frcp(c + 1e-30f);
#pragma unroll
          for (int nr = 0; nr < 4; ++nr)
            if (nr < mcnt) p[mj][nr][q] *= sc;
        }
      }
  }

  // ================= GEMM3: out = P^T @ x ====================================
  // stage P^T: pth[(i>>3)*512 + j*8 + (i&7)], i = 16nr+lc, j = 16mj+4g+q
#pragma unroll
  for (int mj = 0; mj < 4; ++mj)
#pragma unroll
    for (int nr = 0; nr < 4; ++nr)
#pragma unroll
      for (int q = 0; q < 4; ++q)
        pth[((2 * nr + (lc >> 3)) * 64 + 16 * mj + 4 * g + q) * 8 + (lc & 7)] =
            (h16)p[mj][nr][q];
  asm volatile("s_waitcnt lgkmcnt(0)" ::: "memory");

  float* outb = outp + 8192 + (size_t)b * 8192;
#pragma unroll 1
  for (int c = 0; c < 4; ++c) {  // f-chunks of 32
    v4f acc3[4][2];
#pragma unroll
    for (int m = 0; m < 4; ++m)
#pragma unroll
      for (int nn = 0; nn < 2; ++nn) acc3[m][nn] = (v4f){0.f, 0.f, 0.f, 0.f};
#pragma unroll 1
    for (int kk = 0; kk < kk3max; ++kk) {
      h8 ap[4];
#pragma unroll
      for (int m = 0; m < 4; ++m)
        if (m < mcnt)
          ap[m] = *(const h8*)&pth[((4 * kk + g) * 64 + 16 * m + lc) * 8];
#pragma unroll
      for (int nn = 0; nn < 2; ++nn) {
        const int f = 16 * (2 * c + nn) + lc;
        v4f x0, x1;
#pragma unroll
        for (int e = 0; e < 4; ++e) x0[e] = xb[(kk * 32 + 8 * g + e) * 128 + f];
#pragma unroll
        for (int e = 0; e < 4; ++e) x1[e] = xb[(kk * 32 + 8 * g + 4 + e) * 128 + f];
        h8 bxx = cvt8(x0, x1);
#pragma unroll
        for (int m = 0; m < 4; ++m)
          if (m < mcnt)
            acc3[m][nn] = __builtin_amdgcn_mfma_f32_16x16x32_f16(ap[m], bxx, acc3[m][nn], 0, 0, 0);
      }
    }
    // direct stores (rows j>=k store zeros)
#pragma unroll
    for (int m = 0; m < 4; ++m)
#pragma unroll
      for (int nn = 0; nn < 2; ++nn)
#pragma unroll
        for (int q = 0; q < 4; ++q)
          outb[(16 * m + 4 * g + q) * 128 + 16 * (2 * c + nn) + lc] = acc3[m][nn][q];
  }
}

extern "C" void kernel_launch(void* const* d_in, const int* in_sizes, int n_in,
                              void* d_out, int out_size, void* d_ws, size_t ws_size,
                              hipStream_t stream) {
  const float* xf = (const float*)d_in[0];
  const int* ssz = (const int*)d_in[1];
  // d_in[2] = maskB: unused (recomputed from set_size)
  const float* gn = (const float*)d_in[3];
  const float* W1 = (const float*)d_in[4];
  const float* b1 = (const float*)d_in[5];
  const float* W2 = (const float*)d_in[6];
  const float* b2 = (const float*)d_in[7];
  float* outp = (float*)d_out;

  const size_t ws_need = (size_t)(128 * 256 + 256 * 64) * sizeof(h16);  // 98304 B
  const bool use_ws = (d_ws != nullptr) && (ws_size >= ws_need);

  if (use_ws) {
    h16* w1t = (h16*)d_ws;             // [256][128] f16
    h16* w2t = w1t + 128 * 256;        // [64][256]  f16
    prep_w<<<192, 256, 0, stream>>>(W1, W2, w1t, w2t);
    permgen_wave<true><<<2048, 256, 0, stream>>>(xf, ssz, gn, b1, b2, w1t, w2t,
                                                 W1, W2, outp);
  } else {
    permgen_wave<false><<<2048, 256, 0, stream>>>(xf, ssz, gn, b1, b2,
                                                  (const h16*)nullptr,
                                                  (const h16*)nullptr,
                                                  W1, W2, outp);
  }
  // set_size written LAST so nothing can clobber [0:8192).
  write_ss<<<32, 256, 0, stream>>>(ssz, outp);
}

// Round 8
// 470.967 us; speedup vs baseline: 1.3148x; 1.3148x over previous
//
#include <hip/hip_runtime.h>
#include <hip/hip_bf16.h>

// PermutationGenerator: B=8192, N=64, D=128, LATENT=256, TEMP=0.1, 20 Sinkhorn iters.
// d_in (ALL f32): [0] padded [B][64][128], [1] set_size int32 [B], [2] maskB (UNUSED),
//       [3] gumbel [B][64][64], [4] W1 [128][256], [5] b1 [256],
//       [6] W2 [256][64], [7] b2 [64]
// d_out f32: [0:8192] set_size, then permuted [B][64][128].
//
// R8 = R6 two-kernel split with P0 stashed as F32 (f16 roundtrip broke Sinkhorn's
// dynamic range: col-norm resurrects entries ~40+ nats below rowmax; f16 flushes
// anything below ~17 nats -> zeroed columns -> 7.1 absmax). P0 f32 [64][64] =
// 16KB fits in batch b's own 32KB out region, overwritten by kernel B later.
//  A) mlp_init: GEMM1+GEMM2+gumbel/mask/rowmax/exp -> P0 (f32, fragment-order,
//     64B/thread coalesced).
//  B) sink_out: reload P0 into identical fragment registers, 20 Sinkhorn iters
//     (1 barrier/iter), GEMM3, coalesced stores. x loads issued at entry,
//     consumed after Sinkhorn (T14 latency hiding).

typedef _Float16 h16;
typedef h16 h8 __attribute__((ext_vector_type(8)));
typedef h16 h4 __attribute__((ext_vector_type(4)));
typedef __fp16 fp16x2 __attribute__((ext_vector_type(2)));
typedef float v4f __attribute__((ext_vector_type(4)));

template<int CTRL>
__device__ __forceinline__ float dppf(float x) {
  return __int_as_float(__builtin_amdgcn_update_dpp(
      0, __float_as_int(x), CTRL, 0xF, 0xF, true));
}
__device__ __forceinline__ float red16_sum(float x) {
  x += dppf<0xB1>(x);
  x += dppf<0x4E>(x);
  x += dppf<0x124>(x);
  x += dppf<0x128>(x);
  return x;
}
__device__ __forceinline__ float red16_max(float x) {
  x = fmaxf(x, dppf<0xB1>(x));
  x = fmaxf(x, dppf<0x4E>(x));
  x = fmaxf(x, dppf<0x124>(x));
  x = fmaxf(x, dppf<0x128>(x));
  return x;
}
__device__ __forceinline__ float frcp(float x) { return __builtin_amdgcn_rcpf(x); }
__device__ __forceinline__ h8 cvt8(v4f a, v4f b) {
  union { h8 v; fp16x2 p[4]; } u;
  u.p[0] = __builtin_amdgcn_cvt_pkrtz(a[0], a[1]);
  u.p[1] = __builtin_amdgcn_cvt_pkrtz(a[2], a[3]);
  u.p[2] = __builtin_amdgcn_cvt_pkrtz(b[0], b[1]);
  u.p[3] = __builtin_amdgcn_cvt_pkrtz(b[2], b[3]);
  return u.v;
}

__global__ __launch_bounds__(256) void prep_w(const float* __restrict__ W1,
                                              const float* __restrict__ W2,
                                              h16* __restrict__ w1t,
                                              h16* __restrict__ w2t) {
  int t = blockIdx.x * 256 + threadIdx.x;
  if (t < 128 * 256) {               // W1 [128][256] -> w1t [256 lat][128 f]
    int kq = t >> 8, n = t & 255;
    w1t[n * 128 + kq] = (h16)W1[t];
  } else if (t < 128 * 256 + 256 * 64) {  // W2 [256][64] -> w2t [64 j][256 lat]
    int t2 = t - 128 * 256;
    int kq = t2 >> 6, n = t2 & 63;
    w2t[n * 256 + kq] = (h16)W2[t2];
  }
}

// Runs LAST on the stream.
__global__ __launch_bounds__(256) void write_ss(const int* __restrict__ ssz,
                                                float* __restrict__ outp) {
  int b = blockIdx.x * 256 + threadIdx.x;
  if (b < 8192) outp[b] = (float)ssz[b];
}

// ================= Kernel A: MLP + Sinkhorn-init, store P0 (f32) =============
// LDS arena 33792: xh f16 [64][136] -> hh f16 [64][264]
template<bool WSF>
__global__ __launch_bounds__(256) void mlp_init(
    const float* __restrict__ xf,
    const int* __restrict__ ssz,
    const float* __restrict__ gn,
    const float* __restrict__ b1,
    const float* __restrict__ b2,
    const h16* __restrict__ w1t,   // [256][128]
    const h16* __restrict__ w2t,   // [64][256]
    const float* __restrict__ W1f,
    const float* __restrict__ W2f,
    float* __restrict__ outp) {
  __shared__ __align__(16) char smem[33792];
  h16* xh = (h16*)smem;   // [64][136]
  h16* hh = (h16*)smem;   // [64][264]

  const int tid = threadIdx.x, b = blockIdx.x;
  const int w = tid >> 6, lane = tid & 63, g = lane >> 4, lc = lane & 15;
  const int k = ssz[b];
  const int sr = tid >> 2, sseg = tid & 3;

  {  // stage x -> f16 LDS (coalesced 128B/thread)
    const float* src = xf + (size_t)b * 8192 + sr * 128 + sseg * 32;
#pragma unroll
    for (int v = 0; v < 4; ++v)
      *(h8*)&xh[sr * 136 + sseg * 32 + v * 8] =
          cvt8(*(const v4f*)(src + v * 8), *(const v4f*)(src + v * 8 + 4));
  }
  float b1v[4], b2v[4];
#pragma unroll
  for (int n = 0; n < 4; ++n) b1v[n] = b1[w * 64 + n * 16 + lc];
#pragma unroll
  for (int n = 0; n < 4; ++n) b2v[n] = b2[n * 16 + lc];
  __syncthreads();

  // GEMM1 (full, unguarded — x rows >= k are zero in global): wave w -> cols [64w,64w+64)
  v4f acc1[4][4];
#pragma unroll
  for (int m = 0; m < 4; ++m)
#pragma unroll
    for (int n = 0; n < 4; ++n) acc1[m][n] = (v4f){0.f, 0.f, 0.f, 0.f};
#pragma unroll
  for (int kk = 0; kk < 4; ++kk) {
    h8 av[4], bv[4];
#pragma unroll
    for (int m = 0; m < 4; ++m)
      av[m] = *(h8*)&xh[(lc + 16 * m) * 136 + kk * 32 + 8 * g];
#pragma unroll
    for (int n = 0; n < 4; ++n) {
      if (WSF) {
        bv[n] = *(const h8*)&w1t[(w * 64 + n * 16 + lc) * 128 + kk * 32 + 8 * g];
      } else {
        h8 t;
#pragma unroll
        for (int e = 0; e < 8; ++e)
          t[e] = (h16)W1f[(kk * 32 + 8 * g + e) * 256 + (w * 64 + n * 16 + lc)];
        bv[n] = t;
      }
    }
#pragma unroll
    for (int m = 0; m < 4; ++m)
#pragma unroll
      for (int n = 0; n < 4; ++n)
        acc1[m][n] = __builtin_amdgcn_mfma_f32_16x16x32_f16(av[m], bv[n], acc1[m][n], 0, 0, 0);
  }
  __syncthreads();
#pragma unroll
  for (int m = 0; m < 4; ++m)
#pragma unroll
    for (int n = 0; n < 4; ++n)
#pragma unroll
      for (int q = 0; q < 4; ++q)
        hh[(16 * m + 4 * g + q) * 264 + w * 64 + 16 * n + lc] =
            (h16)fmaxf(acc1[m][n][q] + b1v[n], 0.0f);
  __syncthreads();

  // GEMM2 (full): net rows [16w,16w+16); thread owns rows 16w+4g+i, cols 16n+lc
  v4f acc2[4];
#pragma unroll
  for (int n = 0; n < 4; ++n) acc2[n] = (v4f){0.f, 0.f, 0.f, 0.f};
#pragma unroll
  for (int kk = 0; kk < 8; ++kk) {
    h8 av = *(h8*)&hh[(16 * w + lc) * 264 + kk * 32 + 8 * g];
#pragma unroll
    for (int n = 0; n < 4; ++n) {
      h8 bv;
      if (WSF) {
        bv = *(const h8*)&w2t[(n * 16 + lc) * 256 + kk * 32 + 8 * g];
      } else {
        h8 t;
#pragma unroll
        for (int e = 0; e < 8; ++e)
          t[e] = (h16)W2f[(kk * 32 + 8 * g + e) * 64 + (n * 16 + lc)];
        bv = t;
      }
      acc2[n] = __builtin_amdgcn_mfma_f32_16x16x32_f16(av, bv, acc2[n], 0, 0, 0);
    }
  }

  // init: P0 = exp2((la - rowmax)*10*log2e), masked -> 0
  float p[4][4];
#pragma unroll
  for (int i = 0; i < 4; ++i)
#pragma unroll
    for (int n = 0; n < 4; ++n) p[i][n] = 0.0f;
  if (16 * w < k) {
#pragma unroll
    for (int i = 0; i < 4; ++i) {
      const int row = 16 * w + 4 * g + i;
      float la[4];
#pragma unroll
      for (int n = 0; n < 4; ++n) {
        const int col = 16 * n + lc;
        const bool valid = (row < k) && (col < k);
        const float v = acc2[n][i] + b2v[n] + gn[(size_t)b * 4096 + row * 64 + col];
        la[n] = valid ? v : -1e30f;
      }
      float m_ = fmaxf(fmaxf(la[0], la[1]), fmaxf(la[2], la[3]));
      m_ = red16_max(m_);
#pragma unroll
      for (int n = 0; n < 4; ++n)
        p[i][n] = (la[n] > -1e29f) ? exp2f((la[n] - m_) * 14.4269504089f) : 0.0f;
    }
  }

  // store P0 f32 fragment-order: thread tid -> 64B at P0[tid*16]
  float* P0 = outp + 8192 + (size_t)b * 8192;
#pragma unroll
  for (int i = 0; i < 4; ++i) {
    v4f o;
#pragma unroll
    for (int n = 0; n < 4; ++n) o[n] = p[i][n];
    *(v4f*)&P0[tid * 16 + i * 4] = o;
  }
}

// ================= Kernel B: Sinkhorn + GEMM3 + store ========================
// LDS 34944: xth f16 [128][72] @0 | pth f16 [64][72] @18432 | outst f32 [64][128]
// (overlay @0 after GEMM3) | part f32 @32768 (2176B)
__global__ __launch_bounds__(256) void sink_out(
    const float* __restrict__ xf,
    const int* __restrict__ ssz,
    float* __restrict__ outp) {
  __shared__ __align__(16) char smem[34944];
  h16* xth = (h16*)smem;
  h16* pth = (h16*)(smem + 18432);
  float* outst = (float*)smem;
  float* part = (float*)(smem + 32768);

  const int tid = threadIdx.x, b = blockIdx.x;
  const int w = tid >> 6, lane = tid & 63, g = lane >> 4, lc = lane & 15;
  const int sr = tid >> 2, sseg = tid & 3;

  // T14: issue x loads NOW, consume after Sinkhorn (latency hidden)
  v4f xr[8];
  {
    const float* src = xf + (size_t)b * 8192 + sr * 128 + sseg * 32;
#pragma unroll
    for (int v = 0; v < 8; ++v) xr[v] = *(const v4f*)(src + v * 4);
  }

  // load P0 f32 (same fragment mapping as kernel A)
  float p[4][4];
  {
    const float* P0 = outp + 8192 + (size_t)b * 8192;
#pragma unroll
    for (int i = 0; i < 4; ++i) {
      v4f t = *(const v4f*)&P0[tid * 16 + i * 4];
#pragma unroll
      for (int n = 0; n < 4; ++n) p[i][n] = t[n];
    }
  }

  // 20 iterations: row-normalize then col-normalize (exp domain)
#pragma unroll 1
  for (int it = 0; it < 20; ++it) {
#pragma unroll
    for (int i = 0; i < 4; ++i) {  // row norm: DPP-only
      float s = (p[i][0] + p[i][1]) + (p[i][2] + p[i][3]);
      s = red16_sum(s);
      const float sc = frcp(s + 1e-30f);
#pragma unroll
      for (int n = 0; n < 4; ++n) p[i][n] *= sc;
    }
    float cp[4];
#pragma unroll
    for (int n = 0; n < 4; ++n) {  // col partials over this wave's 16 rows
      float c = (p[0][n] + p[1][n]) + (p[2][n] + p[3][n]);
      c += __shfl_xor(c, 16);
      c += __shfl_xor(c, 32);
      cp[n] = c;
    }
    if (lane < 16) {
#pragma unroll
      for (int n = 0; n < 4; ++n)
        part[((it & 1) * 4 + w) * 68 + 16 * n + lc] = cp[n];
    }
    __syncthreads();
#pragma unroll
    for (int n = 0; n < 4; ++n) {
      float cs = 0.0f;
#pragma unroll
      for (int pw = 0; pw < 4; ++pw)
        cs += part[((it & 1) * 4 + pw) * 68 + 16 * n + lc];
      const float sc = frcp(cs + 1e-30f);
#pragma unroll
      for (int i = 0; i < 4; ++i) p[i][n] *= sc;
    }
  }

  // stage P^T and x^T
#pragma unroll
  for (int n = 0; n < 4; ++n) {
    h4 t;
#pragma unroll
    for (int i = 0; i < 4; ++i) t[i] = (h16)p[i][n];
    *(h4*)&pth[(16 * n + lc) * 72 + 16 * w + 4 * g] = t;  // P^T[col j][rows i..]
  }
#pragma unroll
  for (int v = 0; v < 4; ++v)
#pragma unroll
    for (int e = 0; e < 8; ++e) {
      const float xv = (e < 4) ? xr[2 * v][e] : xr[2 * v + 1][e - 4];
      xth[(sseg * 32 + v * 8 + e) * 72 + sr] = (h16)xv;  // x^T[f][i]
    }
  __syncthreads();

  // GEMM3 (full K=64): out = P^T @ x; wave w -> out cols [32w,32w+32)
  v4f acc3[4][2];
#pragma unroll
  for (int m = 0; m < 4; ++m)
#pragma unroll
    for (int nn = 0; nn < 2; ++nn) acc3[m][nn] = (v4f){0.f, 0.f, 0.f, 0.f};
#pragma unroll
  for (int kk = 0; kk < 2; ++kk) {
    h8 av[4], bv[2];
#pragma unroll
    for (int m = 0; m < 4; ++m)
      av[m] = *(h8*)&pth[(lc + 16 * m) * 72 + kk * 32 + 8 * g];
#pragma unroll
    for (int nn = 0; nn < 2; ++nn)
      bv[nn] = *(h8*)&xth[(32 * w + 16 * nn + lc) * 72 + kk * 32 + 8 * g];
#pragma unroll
    for (int m = 0; m < 4; ++m)
#pragma unroll
      for (int nn = 0; nn < 2; ++nn)
        acc3[m][nn] = __builtin_amdgcn_mfma_f32_16x16x32_f16(av[m], bv[nn], acc3[m][nn], 0, 0, 0);
  }
  __syncthreads();  // GEMM3 LDS reads done before outst overlays xth/pth

  // stage output skewed: outst[row][(col + 4*row) & 127]
#pragma unroll
  for (int m = 0; m < 4; ++m)
#pragma unroll
    for (int nn = 0; nn < 2; ++nn)
#pragma unroll
      for (int q = 0; q < 4; ++q) {
        const int row = 16 * m + 4 * g + q;
        const int col = 32 * w + 16 * nn + lc;
        outst[row * 128 + ((col + 4 * row) & 127)] = acc3[m][nn][q];
      }
  __syncthreads();

  {  // coalesced f32 store: 128B/thread (overwrites P0 region with final data)
    float* dst = outp + 8192 + (size_t)b * 8192 + sr * 128 + sseg * 32;
#pragma unroll
    for (int v = 0; v < 8; ++v) {
      const int coff = (sseg * 32 + v * 4 + 4 * sr) & 127;
      *(v4f*)(dst + v * 4) = *(v4f*)&outst[sr * 128 + coff];
    }
  }
}

extern "C" void kernel_launch(void* const* d_in, const int* in_sizes, int n_in,
                              void* d_out, int out_size, void* d_ws, size_t ws_size,
                              hipStream_t stream) {
  const float* xf = (const float*)d_in[0];
  const int* ssz = (const int*)d_in[1];
  // d_in[2] = maskB: unused (recomputed from set_size)
  const float* gn = (const float*)d_in[3];
  const float* W1 = (const float*)d_in[4];
  const float* b1 = (const float*)d_in[5];
  const float* W2 = (const float*)d_in[6];
  const float* b2 = (const float*)d_in[7];
  float* outp = (float*)d_out;

  const size_t ws_need = (size_t)(128 * 256 + 256 * 64) * sizeof(h16);  // 98304 B
  const bool use_ws = (d_ws != nullptr) && (ws_size >= ws_need);

  if (use_ws) {
    h16* w1t = (h16*)d_ws;             // [256][128] f16
    h16* w2t = w1t + 128 * 256;        // [64][256]  f16
    prep_w<<<192, 256, 0, stream>>>(W1, W2, w1t, w2t);
    mlp_init<true><<<8192, 256, 0, stream>>>(xf, ssz, gn, b1, b2, w1t, w2t,
                                             W1, W2, outp);
  } else {
    mlp_init<false><<<8192, 256, 0, stream>>>(xf, ssz, gn, b1, b2,
                                              (const h16*)nullptr,
                                              (const h16*)nullptr,
                                              W1, W2, outp);
  }
  sink_out<<<8192, 256, 0, stream>>>(xf, ssz, outp);
  // set_size written LAST so nothing can clobber [0:8192).
  write_ss<<<32, 256, 0, stream>>>(ssz, outp);
}